// Round 9
// baseline (141.025 us; speedup 1.0000x reference)
//
#include <hip/hip_runtime.h>
#include <stdint.h>

#define KD 256     // K dimension; kernel assumes 256

typedef __attribute__((ext_vector_type(4))) float f32x4;
typedef __attribute__((ext_vector_type(8))) int   i32x8;

// Kernel 1: per-row normalize, convert to fp8 e4m3 (OCP HW cvt); fp32 diag.
// Lane l handles elements [4l, 4l+4). Also zeroes d_out.
__global__ __launch_bounds__(256) void norm_kernel(
    const float* __restrict__ a, const float* __restrict__ b,
    unsigned int* __restrict__ an, unsigned int* __restrict__ bn,
    float* __restrict__ diag, float* __restrict__ out, int D) {
  if (blockIdx.x == 0 && threadIdx.x == 0) out[0] = 0.f;
  const int row = blockIdx.x * 4 + (threadIdx.x >> 6);
  const int l = threadIdx.x & 63;
  const float4 av = ((const float4*)(a + (size_t)row * D))[l];
  const float4 bv = ((const float4*)(b + (size_t)row * D))[l];
  float ssa = av.x*av.x + av.y*av.y + av.z*av.z + av.w*av.w;
  float ssb = bv.x*bv.x + bv.y*bv.y + bv.z*bv.z + bv.w*bv.w;
  float dot = av.x*bv.x + av.y*bv.y + av.z*bv.z + av.w*bv.w;
  for (int off = 1; off < 64; off <<= 1) {
    ssa += __shfl_xor(ssa, off, 64);
    ssb += __shfl_xor(ssb, off, 64);
    dot += __shfl_xor(dot, off, 64);
  }
  const float inva = 1.0f / sqrtf(ssa);
  const float invb = 1.0f / sqrtf(ssb);
  if (l == 0) diag[row] = dot * inva * invb;
  int pa = 0, pb = 0;
  pa = __builtin_amdgcn_cvt_pk_fp8_f32(av.x * inva, av.y * inva, pa, 0);
  pa = __builtin_amdgcn_cvt_pk_fp8_f32(av.z * inva, av.w * inva, pa, 1);
  pb = __builtin_amdgcn_cvt_pk_fp8_f32(bv.x * invb, bv.y * invb, pb, 0);
  pb = __builtin_amdgcn_cvt_pk_fp8_f32(bv.z * invb, bv.w * invb, pb, 1);
  an[(size_t)row * (D / 4) + l] = (unsigned int)pa;
  bn[(size_t)row * (D / 4) + l] = (unsigned int)pb;
}

// Kernel 2: ZERO-LDS fp8 GEMM, mfma_scale_f32_16x16x128_f8f6f4 (scale=1.0).
// Block = 256 thr / 4 waves (2x2 of 64x64 subtiles) on a 128x128 tile;
// persistent over 8 tj (grid 512 = 64 ti x 8 jg; jg = blockIdx&7 pins each
// XCD to one jg -> its L2 holds 8 B-tiles (256 KB) + A (2 MB)).
// A-fragments for the FULL K=256 live in 64 VGPRs (loaded once, direct
// global->VGPR). B-fragments loaded direct global->VGPR per (nt, half).
// NO __shared__, NO __syncthreads: no vmcnt-drain barriers; waves free-run
// and the 32-MFMA-per-tj stream covers B-load latency at 2 waves/SIMD.
// Row-max partials accumulate in registers across all 8 tj (one write per
// block, per-(jg,wn) slot); col-max per tj, per-(ti,wm) slot -> no
// cross-wave combine anywhere.
__global__ __launch_bounds__(256, 2) void gemm_max_kernel(
    const unsigned char* __restrict__ an, const unsigned char* __restrict__ bn,
    const int* __restrict__ labels,
    float* __restrict__ row_part, float* __restrict__ col_part, int B) {
  const int lane = threadIdx.x & 63;
  const int w    = threadIdx.x >> 6;
  const int wm   = w >> 1, wn = w & 1;
  const int jg   = blockIdx.x & 7;      // == XCD id mod 8: B-tile L2 pinning
  const int ti   = blockIdx.x >> 3;
  const int fr   = lane & 15;           // fragment m/n index
  const int hi   = lane >> 4;           // k-quad: lane holds k = hi*32..+31

  // A fragments, full K, direct global->VGPR (64 regs).
  const unsigned char* ga = an + (size_t)(ti * 128 + wm * 64 + fr) * KD + hi * 32;
  i32x8 af[4][2];
  #pragma unroll
  for (int mt = 0; mt < 4; ++mt)
    #pragma unroll
    for (int it = 0; it < 2; ++it)
      af[mt][it] = *(const i32x8*)(ga + (size_t)(mt * 16) * KD + it * 128);

  // Row labels (loop-invariant).
  int li[4][4];
  #pragma unroll
  for (int mt = 0; mt < 4; ++mt)
    #pragma unroll
    for (int r = 0; r < 4; ++r)
      li[mt][r] = labels[ti * 128 + wm * 64 + mt * 16 + hi * 4 + r];

  float rp[4][4];
  #pragma unroll
  for (int mt = 0; mt < 4; ++mt)
    #pragma unroll
    for (int r = 0; r < 4; ++r) rp[mt][r] = -1e9f;

  const int SC = 0x7F7F7F7F;            // E8M0 = 1.0 in all byte slots
  const f32x4 fz = {0.f, 0.f, 0.f, 0.f};

  #pragma unroll 1                      // cap register pressure per tj
  for (int t = 0; t < 8; ++t) {
    const int tj = jg * 8 + t;
    const unsigned char* gb = bn + (size_t)(tj * 128 + wn * 64 + fr) * KD + hi * 32;

    int labc[4];
    #pragma unroll
    for (int nt = 0; nt < 4; ++nt)
      labc[nt] = labels[tj * 128 + wn * 64 + nt * 16 + fr];

    f32x4 acc[4][4];
    #pragma unroll
    for (int nt = 0; nt < 4; ++nt) {
      const i32x8 bf = *(const i32x8*)(gb + (size_t)(nt * 16) * KD);
      #pragma unroll
      for (int mt = 0; mt < 4; ++mt)
        acc[mt][nt] = __builtin_amdgcn_mfma_scale_f32_16x16x128_f8f6f4(
            af[mt][0], bf, fz, 0, 0, 0, SC, 0, SC);
    }
    #pragma unroll
    for (int nt = 0; nt < 4; ++nt) {
      const i32x8 bf = *(const i32x8*)(gb + (size_t)(nt * 16) * KD + 128);
      #pragma unroll
      for (int mt = 0; mt < 4; ++mt)
        acc[mt][nt] = __builtin_amdgcn_mfma_scale_f32_16x16x128_f8f6f4(
            af[mt][1], bf, acc[mt][nt], 0, 0, 0, SC, 0, SC);
    }

    // Masked max epilogue. C/D: col = fr, row = hi*4 + reg.
    float cp[4] = {-1e9f, -1e9f, -1e9f, -1e9f};
    #pragma unroll
    for (int mt = 0; mt < 4; ++mt)
      #pragma unroll
      for (int r = 0; r < 4; ++r) {
        const int l0 = li[mt][r];
        float rm = rp[mt][r];
        #pragma unroll
        for (int nt = 0; nt < 4; ++nt) {
          const float vm = (l0 != labc[nt]) ? acc[mt][nt][r] : -1e9f;
          rm = fmaxf(rm, vm);
          cp[nt] = fmaxf(cp[nt], vm);
        }
        rp[mt][r] = rm;
      }

    // Col partials: fold the 4 hi-lane groups (2 shuffles), write per-wm slot.
    #pragma unroll
    for (int nt = 0; nt < 4; ++nt) {
      float c = cp[nt];
      c = fmaxf(c, __shfl_xor(c, 16, 64));
      c = fmaxf(c, __shfl_xor(c, 32, 64));
      if (lane < 16)
        col_part[(size_t)(ti * 2 + wm) * B + tj * 128 + wn * 64 + nt * 16 + fr] = c;
    }
  }

  // Row partials: fold the 16 fr-lanes (4 shuffles), write per-(jg,wn) slot.
  #pragma unroll
  for (int mt = 0; mt < 4; ++mt)
    #pragma unroll
    for (int r = 0; r < 4; ++r) {
      float v = rp[mt][r];
      #pragma unroll
      for (int off = 1; off < 16; off <<= 1)
        v = fmaxf(v, __shfl_xor(v, off, 64));
      if (fr == 0)
        row_part[(size_t)(jg * 2 + wn) * B +
                 ti * 128 + wm * 64 + mt * 16 + hi * 4 + r] = v;
    }
}

// Kernel 3: reduce per-tile maxes -> M; hard-negative threshold + pos_valid;
// per-row loss; one float atomicAdd of blocksum/B into d_out (zeroed by norm).
// Row direction: Trow=16 slots; col direction: Tcol=128 slots.
__global__ __launch_bounds__(256) void finalize_kernel(
    const float* __restrict__ row_part, const float* __restrict__ col_part,
    const float* __restrict__ diag, int B, int Trow, int Tcol,
    float* __restrict__ out) {
  const int v = blockIdx.x * 256 + threadIdx.x;
  const bool isrow = v < B;
  const int i = isrow ? v : v - B;
  const float* part = isrow ? row_part : col_part;
  const int T = isrow ? Trow : Tcol;
  float m = -1e9f;
  for (int t = 0; t < T; ++t) m = fmaxf(m, part[(size_t)t * B + i]);
  const float d = diag[i];
  float loss = 0.f;
  if ((d < 1.0f - 1e-5f) && (m + 0.2f > d)) {
    loss = fmaxf(0.2f * d * d - 0.7f * d + 0.5f, 0.f) +
           fmaxf(0.9f * m * m - 0.4f * m + 0.03f, 0.f);
  }
  for (int off = 1; off < 64; off <<= 1) loss += __shfl_xor(loss, off, 64);
  __shared__ float ssum[4];
  if ((threadIdx.x & 63) == 0) ssum[threadIdx.x >> 6] = loss;
  __syncthreads();
  if (threadIdx.x == 0)
    atomicAdd(out, (ssum[0] + ssum[1] + ssum[2] + ssum[3]) / (float)B);
}

extern "C" void kernel_launch(void* const* d_in, const int* in_sizes, int n_in,
                              void* d_out, int out_size, void* d_ws, size_t ws_size,
                              hipStream_t stream) {
  const float* a      = (const float*)d_in[0];
  const float* b      = (const float*)d_in[1];
  const int*   labels = (const int*)d_in[2];
  const int B = in_sizes[2];
  const int D = in_sizes[0] / B;       // 256
  const int Trow = 16;                 // jg(8) x wn(2)
  const int Tcol = (B / 128) * 2;      // ti(64) x wm(2) = 128

  char* ws = (char*)d_ws;
  unsigned char* an = (unsigned char*)ws;                    // B*D fp8
  unsigned char* bn = (unsigned char*)(ws + (size_t)B * D);  // B*D fp8
  float* diag     = (float*)(ws + (size_t)2 * B * D);        // B*4
  float* row_part = diag + B;                                // Trow*B*4
  float* col_part = row_part + (size_t)Trow * B;             // Tcol*B*4

  norm_kernel<<<B / 4, 256, 0, stream>>>(a, b, (unsigned int*)an,
                                         (unsigned int*)bn, diag,
                                         (float*)d_out, D);

  gemm_max_kernel<<<(B / 128) * 8, 256, 0, stream>>>(
      an, bn, labels, row_part, col_part, B);

  finalize_kernel<<<(2 * B) / 256, 256, 0, stream>>>(
      row_part, col_part, diag, B, Trow, Tcol, (float*)d_out);
}

// Round 10
// 126.006 us; speedup vs baseline: 1.1192x; 1.1192x over previous
//
#include <hip/hip_runtime.h>
#include <stdint.h>

#define KD 256     // K dimension; kernel assumes 256

typedef __attribute__((ext_vector_type(4))) float f32x4;
typedef __attribute__((ext_vector_type(8))) int   i32x8;

// Fragment-major fp8 layout: byte (row,k) -> g=row>>4, fr=row&15, it=k>>7,
// hi=(k>>5)&3, j=k&31 at offset g*4096 + it*2048 + hi*512 + fr*32 + j.
// A wave's (16-row-group, K-half) fragment = 2 KB contiguous, addr = base+lane*32.

// Kernel 1: per-row normalize, convert to fp8 e4m3 (OCP HW cvt) and store in
// fragment-major layout; fp32 diag. Lane l handles k=4l..4l+3. Zeroes d_out.
__global__ __launch_bounds__(256) void norm_kernel(
    const float* __restrict__ a, const float* __restrict__ b,
    unsigned int* __restrict__ an, unsigned int* __restrict__ bn,
    float* __restrict__ diag, float* __restrict__ out, int D) {
  if (blockIdx.x == 0 && threadIdx.x == 0) out[0] = 0.f;
  const int row = blockIdx.x * 4 + (threadIdx.x >> 6);
  const int l = threadIdx.x & 63;
  const float4 av = ((const float4*)(a + (size_t)row * D))[l];
  const float4 bv = ((const float4*)(b + (size_t)row * D))[l];
  float ssa = av.x*av.x + av.y*av.y + av.z*av.z + av.w*av.w;
  float ssb = bv.x*bv.x + bv.y*bv.y + bv.z*bv.z + bv.w*bv.w;
  float dot = av.x*bv.x + av.y*bv.y + av.z*bv.z + av.w*bv.w;
  for (int off = 1; off < 64; off <<= 1) {
    ssa += __shfl_xor(ssa, off, 64);
    ssb += __shfl_xor(ssb, off, 64);
    dot += __shfl_xor(dot, off, 64);
  }
  const float inva = 1.0f / sqrtf(ssa);
  const float invb = 1.0f / sqrtf(ssb);
  if (l == 0) diag[row] = dot * inva * invb;
  int pa = 0, pb = 0;
  pa = __builtin_amdgcn_cvt_pk_fp8_f32(av.x * inva, av.y * inva, pa, 0);
  pa = __builtin_amdgcn_cvt_pk_fp8_f32(av.z * inva, av.w * inva, pa, 1);
  pb = __builtin_amdgcn_cvt_pk_fp8_f32(bv.x * invb, bv.y * invb, pb, 0);
  pb = __builtin_amdgcn_cvt_pk_fp8_f32(bv.z * invb, bv.w * invb, pb, 1);
  // fragment-major u32 index: k=4l -> it=l>>5, hi=(l>>3)&3, word=l&7
  const int idx = (row >> 4) * 1024 + (l >> 5) * 512 + ((l >> 3) & 3) * 128 +
                  (row & 15) * 8 + (l & 7);
  an[idx] = (unsigned int)pa;
  bn[idx] = (unsigned int)pb;
}

// Kernel 2: ZERO-LDS fp8 GEMM, mfma_scale_f32_16x16x128_f8f6f4 (scale=1.0),
// operands in fragment-major layout -> every A/B fragment load is
// base + lane*32: 2 KB fully contiguous per wave (no TA scatter; R9's
// strided loads touched ~32 cache lines per instruction and pinned the L1
// port). Block = 4 waves on a 128x128 tile, persistent over 8 tj
// (jg = blockIdx&7 pins B-tiles per XCD). A-fragments (full K=256) in 64
// VGPRs; NO __shared__, NO __syncthreads. Row-max partials in registers
// across all tj; col-max per tj. Per-wave slots -> no cross-wave combine.
__global__ __launch_bounds__(256, 2) void gemm_max_kernel(
    const unsigned char* __restrict__ an, const unsigned char* __restrict__ bn,
    const int* __restrict__ labels,
    float* __restrict__ row_part, float* __restrict__ col_part, int B) {
  const int lane = threadIdx.x & 63;
  const int w    = threadIdx.x >> 6;
  const int wm   = w >> 1, wn = w & 1;
  const int jg   = blockIdx.x & 7;      // XCD-pinned B-tile group
  const int ti   = blockIdx.x >> 3;
  const int fr   = lane & 15;
  const int hi   = lane >> 4;
  const int lo32 = lane * 32;           // fragment-major lane offset

  // A fragments, full K, coalesced: group g = ti*8 + wm*4 + mt.
  i32x8 af[4][2];
  #pragma unroll
  for (int mt = 0; mt < 4; ++mt) {
    const unsigned char* gaf = an + (size_t)(ti * 8 + wm * 4 + mt) * 4096 + lo32;
    af[mt][0] = *(const i32x8*)(gaf);
    af[mt][1] = *(const i32x8*)(gaf + 2048);
  }

  // Row labels (loop-invariant).
  int li[4][4];
  #pragma unroll
  for (int mt = 0; mt < 4; ++mt)
    #pragma unroll
    for (int r = 0; r < 4; ++r)
      li[mt][r] = labels[ti * 128 + wm * 64 + mt * 16 + hi * 4 + r];

  float rp[4][4];
  #pragma unroll
  for (int mt = 0; mt < 4; ++mt)
    #pragma unroll
    for (int r = 0; r < 4; ++r) rp[mt][r] = -1e9f;

  const int SC = 0x7F7F7F7F;            // E8M0 = 1.0 in all byte slots
  const f32x4 fz = {0.f, 0.f, 0.f, 0.f};

  #pragma unroll 1                      // cap register pressure per tj
  for (int t = 0; t < 8; ++t) {
    const int tj = jg * 8 + t;
    const unsigned char* gbb = bn + (size_t)(tj * 8 + wn * 4) * 4096 + lo32;

    int labc[4];
    #pragma unroll
    for (int nt = 0; nt < 4; ++nt)
      labc[nt] = labels[tj * 128 + wn * 64 + nt * 16 + fr];

    f32x4 acc[4][4];
    #pragma unroll
    for (int nt = 0; nt < 4; ++nt) {
      const i32x8 bf = *(const i32x8*)(gbb + (size_t)nt * 4096);
      #pragma unroll
      for (int mt = 0; mt < 4; ++mt)
        acc[mt][nt] = __builtin_amdgcn_mfma_scale_f32_16x16x128_f8f6f4(
            af[mt][0], bf, fz, 0, 0, 0, SC, 0, SC);
    }
    #pragma unroll
    for (int nt = 0; nt < 4; ++nt) {
      const i32x8 bf = *(const i32x8*)(gbb + (size_t)nt * 4096 + 2048);
      #pragma unroll
      for (int mt = 0; mt < 4; ++mt)
        acc[mt][nt] = __builtin_amdgcn_mfma_scale_f32_16x16x128_f8f6f4(
            af[mt][1], bf, acc[mt][nt], 0, 0, 0, SC, 0, SC);
    }

    // Masked max epilogue. C/D: col = fr, row = hi*4 + reg.
    float cp[4] = {-1e9f, -1e9f, -1e9f, -1e9f};
    #pragma unroll
    for (int mt = 0; mt < 4; ++mt)
      #pragma unroll
      for (int r = 0; r < 4; ++r) {
        const int l0 = li[mt][r];
        float rm = rp[mt][r];
        #pragma unroll
        for (int nt = 0; nt < 4; ++nt) {
          const float vm = (l0 != labc[nt]) ? acc[mt][nt][r] : -1e9f;
          rm = fmaxf(rm, vm);
          cp[nt] = fmaxf(cp[nt], vm);
        }
        rp[mt][r] = rm;
      }

    // Col partials: fold the 4 hi-lane groups (2 shuffles), write per-wm slot.
    #pragma unroll
    for (int nt = 0; nt < 4; ++nt) {
      float c = cp[nt];
      c = fmaxf(c, __shfl_xor(c, 16, 64));
      c = fmaxf(c, __shfl_xor(c, 32, 64));
      if (lane < 16)
        col_part[(size_t)(ti * 2 + wm) * B + tj * 128 + wn * 64 + nt * 16 + fr] = c;
    }
  }

  // Row partials: fold the 16 fr-lanes (4 shuffles), write per-(jg,wn) slot.
  #pragma unroll
  for (int mt = 0; mt < 4; ++mt)
    #pragma unroll
    for (int r = 0; r < 4; ++r) {
      float v = rp[mt][r];
      #pragma unroll
      for (int off = 1; off < 16; off <<= 1)
        v = fmaxf(v, __shfl_xor(v, off, 64));
      if (fr == 0)
        row_part[(size_t)(jg * 2 + wn) * B +
                 ti * 128 + wm * 64 + mt * 16 + hi * 4 + r] = v;
    }
}

// Kernel 3: reduce per-tile maxes -> M; hard-negative threshold + pos_valid;
// per-row loss; one float atomicAdd of blocksum/B into d_out (zeroed by norm).
__global__ __launch_bounds__(256) void finalize_kernel(
    const float* __restrict__ row_part, const float* __restrict__ col_part,
    const float* __restrict__ diag, int B, int Trow, int Tcol,
    float* __restrict__ out) {
  const int v = blockIdx.x * 256 + threadIdx.x;
  const bool isrow = v < B;
  const int i = isrow ? v : v - B;
  const float* part = isrow ? row_part : col_part;
  const int T = isrow ? Trow : Tcol;
  float m = -1e9f;
  for (int t = 0; t < T; ++t) m = fmaxf(m, part[(size_t)t * B + i]);
  const float d = diag[i];
  float loss = 0.f;
  if ((d < 1.0f - 1e-5f) && (m + 0.2f > d)) {
    loss = fmaxf(0.2f * d * d - 0.7f * d + 0.5f, 0.f) +
           fmaxf(0.9f * m * m - 0.4f * m + 0.03f, 0.f);
  }
  for (int off = 1; off < 64; off <<= 1) loss += __shfl_xor(loss, off, 64);
  __shared__ float ssum[4];
  if ((threadIdx.x & 63) == 0) ssum[threadIdx.x >> 6] = loss;
  __syncthreads();
  if (threadIdx.x == 0)
    atomicAdd(out, (ssum[0] + ssum[1] + ssum[2] + ssum[3]) / (float)B);
}

extern "C" void kernel_launch(void* const* d_in, const int* in_sizes, int n_in,
                              void* d_out, int out_size, void* d_ws, size_t ws_size,
                              hipStream_t stream) {
  const float* a      = (const float*)d_in[0];
  const float* b      = (const float*)d_in[1];
  const int*   labels = (const int*)d_in[2];
  const int B = in_sizes[2];
  const int D = in_sizes[0] / B;       // 256
  const int Trow = 16;                 // jg(8) x wn(2)
  const int Tcol = (B / 128) * 2;      // ti(64) x wm(2) = 128

  char* ws = (char*)d_ws;
  unsigned char* an = (unsigned char*)ws;                    // B*D fp8 (frag-major)
  unsigned char* bn = (unsigned char*)(ws + (size_t)B * D);  // B*D fp8 (frag-major)
  float* diag     = (float*)(ws + (size_t)2 * B * D);        // B*4
  float* row_part = diag + B;                                // Trow*B*4
  float* col_part = row_part + (size_t)Trow * B;             // Tcol*B*4

  norm_kernel<<<B / 4, 256, 0, stream>>>(a, b, (unsigned int*)an,
                                         (unsigned int*)bn, diag,
                                         (float*)d_out, D);

  gemm_max_kernel<<<(B / 128) * 8, 256, 0, stream>>>(
      an, bn, labels, row_part, col_part, B);

  finalize_kernel<<<(2 * B) / 256, 256, 0, stream>>>(
      row_part, col_part, diag, B, Trow, Tcol, (float*)d_out);
}